// Round 13
// baseline (258.279 us; speedup 1.0000x reference)
//
#include <hip/hip_runtime.h>
#include <stdio.h>
#include <stdint.h>

// Problem constants
#define BB 2
#define SS 2048
#define ED 1024
#define HH 16
#define HDD 64
#define MROWS 4096            // BB*SS
#define NW_ELEM 1048576u      // ED*ED

typedef unsigned short ushortT;
typedef __attribute__((ext_vector_type(8))) short bf16x8;
typedef __attribute__((ext_vector_type(4))) float f32x4;
typedef __attribute__((ext_vector_type(16))) float f32x16;

// ws layout (ushort elems from base)
#define U_WHI 0u
#define U_WLO 4194304u
#define U_XQ  8388608u
#define U_XK  12582912u
#define U_XV  16777216u
#define U_QH  20971520u
#define U_KH  25165824u
#define U_VH  29360128u       // ends at 33554432 ushort = 64 MiB
// byte offsets
#define LP_OFF  33554432u     // lsum partials (512 KB) inside freed XV region
#define P0_OFF  67108864u     // partial octx half0, f32, 16 MiB  (radix hist lives here pre-attn)
#define P1_OFF  83886080u     // partial octx half1, f32, 16 MiB (ends 96 MiB)
#define HIST_BYTES 135168u    // (2*4*4096 + 4*256) u32
#define SMALL_OFF  100663296u
#define ABS_OFF    SMALL_OFF
#define MSK_OFF    (SMALL_OFF + 32u)
#define CNT_OFF    (SMALL_OFF + 64u)
#define WS_NEEDED  (SMALL_OFF + 96u)

#define SC44 17592186044416.0f               // 2^44
#define INV44 (1.0 / 17592186044416.0)
#define QSCALE 0.18033688011112042f          // 0.125 * log2(e)

__device__ __forceinline__ const float* wsel(int w, const float* W0, const float* W1,
                                             const float* W2, const float* W3) {
  return w == 0 ? W0 : w == 1 ? W1 : w == 2 ? W2 : W3;
}

// bf16 RTNE helpers
__device__ __forceinline__ ushortT f2bf(float x) {
  unsigned u = __float_as_uint(x);
  unsigned r = (u + 0x7FFFu + ((u >> 16) & 1u)) >> 16;
  return (ushortT)r;
}
__device__ __forceinline__ float bf2f(ushortT b) {
  return __uint_as_float(((unsigned)b) << 16);
}
__device__ __forceinline__ void bsplit(float x, ushortT& h, ushortT& l) {
  ushortT hb = f2bf(x);
  float hf = bf2f(hb);
  h = hb;
  l = f2bf(x - hf);
}
__device__ __forceinline__ unsigned pkbf(float a, float b) {
  unsigned r;
  asm("v_cvt_pk_bf16_f32 %0, %1, %2" : "=v"(r) : "v"(a), "v"(b));
  return r;
}
__device__ __forceinline__ void plswap(unsigned& a, unsigned& b) {
  asm("v_permlane32_swap_b32 %0, %1" : "+v"(a), "+v"(b));
}
// raw 2^x. MUST be compiler-visible (TRANS-use hazard needs wait states) —
// bare inline-asm v_exp_f32 caused sporadic stale reads (R8 failure).
__device__ __forceinline__ float fexp2(float x) {
#if __has_builtin(__builtin_amdgcn_exp2f)
  return __builtin_amdgcn_exp2f(x);
#else
  float r;
  asm("v_exp_f32 %0, %1\n\ts_nop 1" : "=v"(r) : "v"(x));
  return r;
#endif
}

// async global->LDS, 16B/lane
__device__ __forceinline__ void gld_lds16(const ushortT* g, ushortT* s) {
  __builtin_amdgcn_global_load_lds((__attribute__((address_space(1))) void*)g,
                                   (__attribute__((address_space(3))) void*)s, 16, 0, 0);
}

// counted vmem wait (literal immediates only)
template <int N> __device__ __forceinline__ void waitv() {
  if constexpr (N == 0) asm volatile("s_waitcnt vmcnt(0)" ::: "memory");
  else if constexpr (N == 4) asm volatile("s_waitcnt vmcnt(4)" ::: "memory");
  else if constexpr (N == 6) asm volatile("s_waitcnt vmcnt(6)" ::: "memory");
}
__device__ __forceinline__ void pipe_barrier() {
  __builtin_amdgcn_s_barrier();
  __builtin_amdgcn_sched_barrier(0);
}

__device__ __forceinline__ float get_thr(const unsigned long long* sAbs, int w) {
  return 0.7f * (float)((double)sAbs[w] * INV44 / 1048576.0);
}
__device__ __forceinline__ float get_scale(const unsigned long long* sMsk,
                                           const unsigned* cnt, int w) {
  double s = (double)sMsk[w] * INV44;
  return (float)s / fmaxf((float)cnt[w], 1.0f);
}

// ---------- radix select helpers (exact kth, deterministic) ----------
// 4096-bin suffix select: thread t owns bins [16t,16t+16). Returns bin, updates k.
__device__ __forceinline__ unsigned scan_sel4k(const unsigned* hist, unsigned& k,
                                               unsigned* sh, int t) {
  unsigned loc[16];
  unsigned tsum = 0;
#pragma unroll
  for (int i = 0; i < 16; i++) { loc[i] = hist[t * 16 + i]; tsum += loc[i]; }
  __syncthreads();
  sh[t] = tsum;
  __syncthreads();
  for (int off = 1; off < 256; off <<= 1) {
    unsigned add = (t + off < 256) ? sh[t + off] : 0u;
    __syncthreads();
    sh[t] += add;
    __syncthreads();
  }
  int selt = __syncthreads_count((int)(sh[t] >= k)) - 1;
  if (t == selt) {
    unsigned cum = (selt < 255) ? sh[selt + 1] : 0u;
    unsigned kk = k;
    int bi = 0;
#pragma unroll 1
    for (int i = 15; i >= 0; --i) {
      cum += loc[i];
      if (cum >= kk) { bi = i; kk = kk - (cum - loc[i]); break; }
    }
    sh[0] = (unsigned)(selt * 16 + bi);
    sh[1] = kk;
  }
  __syncthreads();
  unsigned sel = sh[0];
  k = sh[1];
  __syncthreads();
  return sel;
}

// 256-bin suffix select
__device__ __forceinline__ unsigned scan_sel256(const unsigned* hist, unsigned& k,
                                                unsigned* sh, int t) {
  unsigned myv = hist[t];
  __syncthreads();
  sh[t] = myv;
  __syncthreads();
  for (int off = 1; off < 256; off <<= 1) {
    unsigned add = (t + off < 256) ? sh[t + off] : 0u;
    __syncthreads();
    sh[t] += add;
    __syncthreads();
  }
  int sel = __syncthreads_count((int)(sh[t] >= k)) - 1;
  unsigned suf = sh[sel];
  k -= (suf - hist[sel]);
  __syncthreads();
  return (unsigned)sel;
}

// ---------- input prep helpers ----------
__device__ __forceinline__ void ln_unit(const float* __restrict__ query,
                                        const float* __restrict__ g,
                                        const float* __restrict__ b,
                                        ushortT* __restrict__ Xq,
                                        int row, int t, float* red) {
  float4 v = *(const float4*)&query[(size_t)row * ED + t * 4];
  float s = v.x + v.y + v.z + v.w;
#pragma unroll
  for (int m = 32; m; m >>= 1) s += __shfl_xor(s, m, 64);
  if ((t & 63) == 0) red[t >> 6] = s;
  __syncthreads();
  float mu = (red[0] + red[1] + red[2] + red[3]) * (1.0f / 1024.0f);
  float dx = v.x - mu, dy = v.y - mu, dz = v.z - mu, dw = v.w - mu;
  float s2 = dx * dx + dy * dy + dz * dz + dw * dw;
#pragma unroll
  for (int m = 32; m; m >>= 1) s2 += __shfl_xor(s2, m, 64);
  if ((t & 63) == 0) red[4 + (t >> 6)] = s2;
  __syncthreads();
  float var = (red[4] + red[5] + red[6] + red[7]) * (1.0f / 1024.0f);
  float inv = rsqrtf(var + 1e-5f);
  float4 gg = *(const float4*)&g[t * 4];
  float4 bb = *(const float4*)&b[t * 4];
  float ys[4] = {dx * inv * gg.x + bb.x, dy * inv * gg.y + bb.y,
                 dz * inv * gg.z + bb.z, dw * inv * gg.w + bb.w};
  ushort4 h4;
#pragma unroll
  for (int c = 0; c < 4; c++) ((ushortT*)&h4)[c] = f2bf(ys[c]);
  *(ushort4*)&Xq[(size_t)row * ED + t * 4] = h4;
}

__device__ __forceinline__ void cast_unit(const float* __restrict__ src,
                                          ushortT* __restrict__ dst, int idx, int t) {
  const int i = (idx * 256 + t) * 4;
  float4 v = *(const float4*)&src[i];
  ushort4 h4;
  h4.x = f2bf(v.x); h4.y = f2bf(v.y); h4.z = f2bf(v.z); h4.w = f2bf(v.w);
  *(ushort4*)&dst[i] = h4;
}

// ---------- fused: LN(query)/cast(key,value) + |W| stats (independent work) ----------
__global__ __launch_bounds__(256) void k_pre(const float* __restrict__ query,
                                             const float* __restrict__ key,
                                             const float* __restrict__ value,
                                             const float* __restrict__ g,
                                             const float* __restrict__ b,
                                             const float* W0, const float* W1,
                                             const float* W2, const float* W3,
                                             ushortT* __restrict__ Xq,
                                             ushortT* __restrict__ Xk,
                                             ushortT* __restrict__ Xv,
                                             unsigned long long* sAbs) {
  const int t = threadIdx.x, bid = blockIdx.x;
  __shared__ float red[8];
  __shared__ unsigned long long sd[256];
  if (bid < 4096) {
    ln_unit(query, g, b, Xq, bid, t, red);
  } else if (bid < 8192) {
    cast_unit(key, Xk, bid - 4096, t);
  } else if (bid < 12288) {
    cast_unit(value, Xv, bid - 8192, t);
  } else {
    const int c = bid - 12288, w = c >> 8;
    const float* W = wsel(w, W0, W1, W2, W3) + (c & 255) * 4096;
    unsigned long long s = 0;
#pragma unroll
    for (int r = 0; r < 4; r++) {
      float4 v = *(const float4*)(W + (t + 256 * r) * 4);
      s += (unsigned long long)(fabsf(v.x) * SC44);
      s += (unsigned long long)(fabsf(v.y) * SC44);
      s += (unsigned long long)(fabsf(v.z) * SC44);
      s += (unsigned long long)(fabsf(v.w) * SC44);
    }
    sd[t] = s;
    __syncthreads();
    for (int off = 128; off > 0; off >>= 1) {
      if (t < off) sd[t] += sd[t + off];
      __syncthreads();
    }
    if (!t) atomicAdd(&sAbs[w], sd[0]);
  }
}

// ---------- masked sum/count (grid 512 x 4, 2048 elems/block) ----------
__global__ __launch_bounds__(256) void k_masked(const float* W0, const float* W1,
                                                const float* W2, const float* W3,
                                                const unsigned long long* sAbs,
                                                unsigned long long* sMsk, unsigned* sCnt) {
  const int w = blockIdx.y, t = threadIdx.x;
  const float thr = get_thr(sAbs, w);
  const float* W = wsel(w, W0, W1, W2, W3) + blockIdx.x * 2048;
  unsigned long long s = 0;
  unsigned c = 0;
#pragma unroll
  for (int r = 0; r < 2; r++) {
    float4 v = *(const float4*)(W + (t + 256 * r) * 4);
    float xs[4] = {v.x, v.y, v.z, v.w};
#pragma unroll
    for (int q = 0; q < 4; q++) {
      float a = fabsf(xs[q]);
      if (a > thr) { s += (unsigned long long)(a * SC44); c++; }
    }
  }
  __shared__ unsigned long long sd[256];
  __shared__ unsigned sc[256];
  sd[t] = s; sc[t] = c;
  __syncthreads();
  for (int off = 128; off > 0; off >>= 1) {
    if (t < off) { sd[t] += sd[t + off]; sc[t] += sc[t + off]; }
    __syncthreads();
  }
  if (!t) { atomicAdd(&sMsk[w], sd[0]); atomicAdd(&sCnt[w], sc[0]); }
}

// ---------- 3-pass radix histogram (12/12/8 bits), grid 512 x 4 ----------
// histG u32 layout: H0[w][4096] | H1[w][4096] | H2[w][256]
template <int PASS>
__global__ __launch_bounds__(256) void k_histP(const float* W0, const float* W1,
                                               const float* W2, const float* W3,
                                               const unsigned long long* sAbs,
                                               const unsigned long long* sMsk,
                                               const unsigned* sCnt,
                                               unsigned* histG) {
  constexpr int NB = (PASS == 2) ? 256 : 4096;
  const int w = blockIdx.y, t = threadIdx.x;
  __shared__ unsigned sh[256];
  __shared__ unsigned hl[NB];
  const float thr = get_thr(sAbs, w);
  const float scale = get_scale(sMsk, sCnt, w);
  unsigned* H0 = histG + w * 4096;
  unsigned* H1 = histG + 4 * 4096 + w * 4096;
  unsigned* H2 = histG + 8 * 4096 + w * 256;

  unsigned k = (w == 3) ? 104857u : 52428u;
  unsigned prefix = 0;
  if constexpr (PASS >= 1) prefix = scan_sel4k(H0, k, sh, t);
  if constexpr (PASS >= 2) prefix = (prefix << 12) | scan_sel4k(H1, k, sh, t);

  for (int i = t; i < NB; i += 256) hl[i] = 0;
  __syncthreads();

  const float* W = wsel(w, W0, W1, W2, W3) + blockIdx.x * 2048;
#pragma unroll
  for (int r = 0; r < 2; r++) {
    float4 v = *(const float4*)(W + (t + 256 * r) * 4);
    float xs[4] = {v.x, v.y, v.z, v.w};
#pragma unroll
    for (int q = 0; q < 4; q++) {
      float x = xs[q];
      float a = fabsf(x);
      float wq = (a > thr) ? copysignf(scale, x) : 0.0f;
      unsigned bits = __float_as_uint(fabsf(x - wq));
      if constexpr (PASS == 0) {
        atomicAdd(&hl[bits >> 20], 1u);
      } else if constexpr (PASS == 1) {
        if ((bits >> 20) == prefix) atomicAdd(&hl[(bits >> 8) & 4095u], 1u);
      } else {
        if ((bits >> 8) == prefix) atomicAdd(&hl[bits & 255u], 1u);
      }
    }
  }
  __syncthreads();
  unsigned* HG = (PASS == 0) ? H0 : (PASS == 1) ? H1 : H2;
  for (int i = t; i < NB; i += 256)
    if (hl[i]) atomicAdd(&HG[i], hl[i]);
}

// ---------- build W_eff, split to bf16 hi/lo ----------
__global__ __launch_bounds__(256) void k_weff(const float* W0, const float* W1,
                                              const float* W2, const float* W3,
                                              const unsigned long long* sAbs,
                                              const unsigned long long* sMsk,
                                              const unsigned* sCnt,
                                              const unsigned* histG,
                                              ushortT* Whi, ushortT* Wlo) {
  const int w = blockIdx.y, t = threadIdx.x;
  __shared__ unsigned sh[256];
  const float thr = get_thr(sAbs, w);
  const float scale = get_scale(sMsk, sCnt, w);
  const unsigned* H0 = histG + w * 4096;
  const unsigned* H1 = histG + 4 * 4096 + w * 4096;
  const unsigned* H2 = histG + 8 * 4096 + w * 256;
  unsigned k = (w == 3) ? 104857u : 52428u;
  unsigned p0 = scan_sel4k(H0, k, sh, t);
  unsigned p1 = scan_sel4k(H1, k, sh, t);
  unsigned p2 = scan_sel256(H2, k, sh, t);
  const unsigned kth = (((p0 << 12) | p1) << 8) | p2;

  const unsigned idx = (blockIdx.x * 256 + t) * 4;
  const float* W = wsel(w, W0, W1, W2, W3);
  float4 v = *(const float4*)(W + idx);
  float xs[4] = {v.x, v.y, v.z, v.w};
  ushort4 h4, l4;
#pragma unroll
  for (int c = 0; c < 4; c++) {
    float x = xs[c];
    float a = fabsf(x);
    float wq = (a > thr) ? copysignf(scale, x) : 0.0f;
    float res = x - wq;
    unsigned bits = __float_as_uint(fabsf(res));
    float we = wq + ((bits >= kth) ? res : 0.0f);
    ushortT hh, ll;
    bsplit(we, hh, ll);
    ((ushortT*)&h4)[c] = hh;
    ((ushortT*)&l4)[c] = ll;
  }
  *(ushort4*)&Whi[(size_t)w * NW_ELEM + idx] = h4;
  *(ushort4*)&Wlo[(size_t)w * NW_ELEM + idx] = l4;
}

// ---------- pipelined MFMA GEMM (3-buffer, counted vmcnt) ----------
__device__ __forceinline__ f32x4 mfma16(bf16x8 a, bf16x8 b, f32x4 c) {
  return __builtin_amdgcn_mfma_f32_16x16x32_bf16(a, b, c, 0, 0, 0);
}

template <int MODE, bool ALO, bool WLO, int BK, int MINW>
__global__ __launch_bounds__(256, MINW) void k_gemmP(
    const ushortT* __restrict__ A0, const ushortT* __restrict__ A0l,
    const ushortT* __restrict__ A1,
    const ushortT* __restrict__ Wh, const ushortT* __restrict__ Wl,
    const float* __restrict__ bias0, const float* __restrict__ bias1,
    ushortT* __restrict__ Cb0, ushortT* __restrict__ Cb1,
    float* __restrict__ Cf) {
  constexpr int ABUF = (BK == 64) ? 8192 : 4096;
  constexpr int BBUF = (BK == 64) ? 4096 : 2048;
  constexpr int L = ((BK == 64) ? 4 : 2) * (1 + (ALO ? 1 : 0)) +
                    ((BK == 64) ? 2 : 1) * (1 + (WLO ? 1 : 0));
  constexpr int NT = 1024 / BK;
  __shared__ __align__(16) ushortT sAh[3 * ABUF];
  __shared__ __align__(16) ushortT sAl[ALO ? 3 * ABUF : 8];
  __shared__ __align__(16) ushortT sBh[3 * BBUF];
  __shared__ __align__(16) ushortT sBl[WLO ? 3 * BBUF : 8];

  const int t = threadIdx.x;
  const int w = t >> 6, l = t & 63;
  const int wr = w >> 1, wc = w & 1;

  const int which = (MODE == 0) ? (blockIdx.x >> 9) : 0;
  const int wid = blockIdx.x & 511;
  int id2 = (wid & 7) * 64 + (wid >> 3);   // XCD-chunked, bijective
  const int m0 = (id2 >> 4) * 128, n0 = (id2 & 15) * 64;

  const ushortT* A = (MODE == 0 && which) ? A1 : A0;
  const ushortT* Wha = Wh + (MODE == 0 ? (unsigned)which * NW_ELEM : 0u);
  const float* bias = (MODE == 0 && which) ? bias1 : bias0;

  // staging swizzles
  const int sr = l >> 3, swz = (l & 7) ^ sr;              // BK=64
  const int srow = l >> 2, sgr = (l & 3) ^ ((l >> 3) & 3); // BK=32

  auto stage = [&](int kt, int buf) {
    if constexpr (BK == 64) {
#pragma unroll
      for (int s2 = 0; s2 < 4; s2++) {
        int seg = w * 4 + s2;
        size_t ga = (size_t)(m0 + seg * 8 + sr) * ED + kt * 64 + swz * 8;
        gld_lds16(A + ga, sAh + buf * ABUF + seg * 512);
        if constexpr (ALO) gld_lds16(A0l + ga, sAl + buf * ABUF + seg * 512);
      }
#pragma unroll
      for (int s2 = 0; s2 < 2; s2++) {
        int seg = w * 2 + s2;
        size_t gb = (size_t)(n0 + seg * 8 + sr) * ED + kt * 64 + swz * 8;
        gld_lds16(Wha + gb, sBh + buf * BBUF + seg * 512);
        if constexpr (WLO) gld_lds16(Wl + gb, sBl + buf * BBUF + seg * 512);
      }
    } else {
#pragma unroll
      for (int s2 = 0; s2 < 2; s2++) {
        int seg = w * 2 + s2;
        size_t ga = (size_t)(m0 + seg * 16 + srow) * ED + kt * 32 + sgr * 8;
        gld_lds16(A + ga, sAh + buf * ABUF + seg * 512);
        if constexpr (ALO) gld_lds16(A0l + ga, sAl + buf * ABUF + seg * 512);
      }
      {
        size_t gb = (size_t)(n0 + w * 16 + srow) * ED + kt * 32 + sgr * 8;
        gld_lds16(Wha + gb, sBh + buf * BBUF + w * 512);
        if constexpr (WLO) gld_lds16(Wl + gb, sBl + buf * BBUF + w * 512);
      }
    }
  };

  f32x4 acc[4][2];
#pragma unroll
  for (int i = 0; i < 4; i++)
#pragma unroll
    for (int j = 0; j < 2; j++) acc[i][j] = (f32x4){0.0f, 0.0f, 0.0f, 0.0f};

  auto compute = [&](int buf) {
    if constexpr (BK == 64) {
#pragma unroll
      for (int ks = 0; ks < 2; ks++) {
        bf16x8 ah[4], al[4], bh2[2], bl2[2];
        const int G = ks * 4 + (l >> 4);
#pragma unroll
        for (int i = 0; i < 4; i++) {
          int r = wr * 64 + i * 16 + (l & 15);
          int off = buf * ABUF + r * 64 + ((G ^ (l & 7)) << 3);
          ah[i] = *(const bf16x8*)&sAh[off];
          if constexpr (ALO) al[i] = *(const bf16x8*)&sAl[off];
        }
#pragma unroll
        for (int j = 0; j < 2; j++) {
          int r = wc * 32 + j * 16 + (l & 15);
          int off = buf * BBUF + r * 64 + ((G ^ (l & 7)) << 3);
          bh2[j] = *(const bf16x8*)&sBh[off];
          if constexpr (WLO) bl2[j] = *(const bf16x8*)&sBl[off];
        }
#pragma unroll
        for (int i = 0; i < 4; i++)
#pragma unroll
          for (int j = 0; j < 2; j++) {
            acc[i][j] = mfma16(ah[i], bh2[j], acc[i][j]);
            if constexpr (WLO) acc[i][j] = mfma16(ah[i], bl2[j], acc[i][j]);
            if constexpr (ALO) acc[i][j] = mfma16(al[i], bh2[j], acc[i][j]);
          }
      }
    } else {
      bf16x8 ah[4], al[4], bh2[2], bl2[2];
      const int G = l >> 4;
#pragma unroll
      for (int i = 0; i < 4; i++) {
        int r = wr * 64 + i * 16 + (l & 15);
        int off = buf * ABUF + r * 32 + ((G ^ ((r >> 1) & 3)) << 3);
        ah[i] = *(const bf16x8*)&sAh[off];
        if constexpr (ALO) al[i] = *(const bf16x8*)&sAl[off];
      }
#pragma unroll
      for (int j = 0; j < 2; j++) {
        int r = wc * 32 + j * 16 + (l & 15);
        int off = buf * BBUF + r * 32 + ((G ^ ((r >> 1) & 3)) << 3);
        bh2[j] = *(const bf16x8*)&sBh[off];
        if constexpr (WLO) bl2[j] = *(const bf16x8*)&sBl[off];
      }
#pragma unroll
      for (int i = 0; i < 4; i++)
#pragma unroll
        for (int j = 0; j < 2; j++) {
          acc[i][j] = mfma16(ah[i], bh2[j], acc[i][j]);
          if constexpr (WLO) acc[i][j] = mfma16(ah[i], bl2[j], acc[i][j]);
          if constexpr (ALO) acc[i][j] = mfma16(al[i], bh2[j], acc[i][j]);
        }
    }
  };

  // 3-buffer pipeline, counted vmcnt, raw barriers
  stage(0, 0);
  stage(1, 1);
  for (int kt = 0; kt < NT; ++kt) {
    if (kt < NT - 1) waitv<L>(); else waitv<0>();
    pipe_barrier();
    if (kt + 2 < NT) stage(kt + 2, (kt + 2) % 3);
    __builtin_amdgcn_s_setprio(1);
    compute(kt % 3);
    __builtin_amdgcn_s_setprio(0);
  }

  // epilogue
  const int coln = l & 15, row4 = (l >> 4) * 4;
  float bn[2];
#pragma unroll
  for (int j = 0; j < 2; j++) bn[j] = bias[n0 + wc * 32 + j * 16 + coln];
  const int b_ = m0 >> 11, h_ = n0 >> 6;

  if constexpr (MODE == 1) {
#pragma unroll
    for (int i = 0; i < 4; i++)
#pragma unroll
      for (int j = 0; j < 2; j++) {
        int n = n0 + wc * 32 + j * 16 + coln;
#pragma unroll
        for (int r = 0; r < 4; r++) {
          int m = m0 + wr * 64 + i * 16 + row4 + r;
          Cf[(size_t)m * ED + n] = acc[i][j][r] + bn[j];
        }
      }
  } else if constexpr (MODE == 0) {
    const float osc = (which == 0) ? QSCALE : 1.0f;
    ushortT* C = which ? Cb1 : Cb0;
#pragma unroll
    for (int i = 0; i < 4; i++)
#pragma unroll
      for (int j = 0; j < 2; j++) {
        int hd = wc * 32 + j * 16 + coln;
#pragma unroll
        for (int r = 0; r < 4; r++) {
          int m = m0 + wr * 64 + i * 16 + row4 + r;
          int s_ = m & 2047;
          float y = acc[i][j][r] + bn[j];
          y = (fabsf(y) >= 0.05f) ? y : 0.0f;
          y *= osc;
          C[((size_t)(b_ * HH + h_) * SS + s_) * HDD + hd] = f2bf(y);
        }
      }
  } else {  // MODE 2: V transposed [B,H,HD,S]
#pragma unroll
    for (int i = 0; i < 4; i++)
#pragma unroll
      for (int j = 0; j < 2; j++) {
        int hd = wc * 32 + j * 16 + coln;
        int s0_ = (m0 + wr * 64 + i * 16 + row4) & 2047;
        ushort4 h4;
#pragma unroll
        for (int r = 0; r < 4; r++) {
          float y = acc[i][j][r] + bn[j];
          y = (fabsf(y) >= 0.05f) ? y : 0.0f;
          ((ushortT*)&h4)[r] = f2bf(y);
        }
        *(ushort4*)&Cb0[((size_t)(b_ * HH + h_) * HDD + hd) * SS + s0_] = h4;
      }
  }
}

// ---------- MFMA flash attention: KV-split x2, 2-buffer, builtin exp2 ----------
__device__ __forceinline__ f32x16 mfma32(bf16x8 a, bf16x8 b, f32x16 c) {
  return __builtin_amdgcn_mfma_f32_32x32x16_bf16(a, b, c, 0, 0, 0);
}

// exp (Q pre-scaled by SCALE*log2e) + pack acc into two PV a-frags
__device__ __forceinline__ void exppack(const f32x16& A, float* ls4,
                                        bf16x8& paA, bf16x8& paB) {
  float p[16];
#pragma unroll
  for (int r = 0; r < 16; r++) {
    p[r] = fexp2(A[r]);
    ls4[r & 3] += p[r];
  }
  unsigned c0 = pkbf(p[0], p[1]), c1 = pkbf(p[2], p[3]);
  unsigned c2 = pkbf(p[4], p[5]), c3 = pkbf(p[6], p[7]);
  unsigned c4 = pkbf(p[8], p[9]), c5 = pkbf(p[10], p[11]);
  unsigned c6 = pkbf(p[12], p[13]), c7 = pkbf(p[14], p[15]);
  plswap(c0, c2); plswap(c1, c3); plswap(c4, c6); plswap(c5, c7);
  uint4 ta = make_uint4(c0, c1, c2, c3);
  uint4 tb = make_uint4(c4, c5, c6, c7);
  paA = __builtin_bit_cast(bf16x8, ta);
  paB = __builtin_bit_cast(bf16x8, tb);
}

__global__ __launch_bounds__(256, 4) void k_attn(
    const ushortT* __restrict__ Qh, const ushortT* __restrict__ Kh,
    const ushortT* __restrict__ Vh,
    float* __restrict__ Pp, float* __restrict__ Lp) {
  __shared__ __align__(16) ushortT sK[2 * 4096];
  __shared__ __align__(16) ushortT sV[2 * 4096];

  const int t = threadIdx.x;
  const int w = t >> 6, l = t & 63;
  const int l32 = l & 31, g = l >> 5;

  int id = blockIdx.x;
  int id2 = (id & 7) * 128 + (id >> 3);   // 1024 = 8*128, bijective
  const int bh = id2 >> 5;
  const int qt = (id2 >> 1) & 15;
  const int half = id2 & 1;

  const size_t kqbase = (size_t)bh * (SS * HDD);   // Q,K: [bh][s][64]
  const size_t vbase = (size_t)bh * (HDD * SS);    // V^T: [bh][64][s]
  const int q0 = qt * 128 + w * 32;
  const int sbase = half * 1024;

  bf16x8 qh[4];
  const size_t qrow = kqbase + (size_t)(q0 + l32) * HDD;
#pragma unroll
  for (int ks = 0; ks < 4; ks++) qh[ks] = *(const bf16x8*)&Qh[qrow + ks * 16 + g * 8];

  f32x16 octx0, octx1;
#pragma unroll
  for (int i = 0; i < 16; i++) { octx0[i] = 0.0f; octx1[i] = 0.0f; }
  float ls4[4] = {0.0f, 0.0f, 0.0f, 0.0f};

  const int srow = l >> 3;
  const int sgr = (l & 7) ^ srow;

  auto stageA = [&](int kt, int buf) {
    const int s0 = sbase + kt * 64;
#pragma unroll
    for (int s2 = 0; s2 < 2; s2++) {
      int seg = w * 2 + s2;
      int row = seg * 8 + srow;
      gld_lds16(Kh + kqbase + (size_t)(s0 + row) * HDD + sgr * 8, sK + buf * 4096 + seg * 512);
      gld_lds16(Vh + vbase + (size_t)row * SS + s0 + sgr * 8, sV + buf * 4096 + seg * 512);
    }
  };

  stageA(0, 0);
  __syncthreads();                       // implicit vmcnt(0) drain

  for (int kt = 0; kt < 16; ++kt) {
    if (kt < 15) stageA(kt + 1, (kt + 1) & 1);
    const ushortT* cK = sK + (kt & 1) * 4096;
    const ushortT* cV = sV + (kt & 1) * 4096;

    // QK^T swapped: acc = mfma(A=K, B=Q) -> lane = q-col, rows = j
    f32x16 acc0, acc1;
#pragma unroll
    for (int i = 0; i < 16; i++) { acc0[i] = 0.0f; acc1[i] = 0.0f; }
#pragma unroll
    for (int ks = 0; ks < 4; ks++) {
      int sw = ((ks * 2 + g) ^ (l32 & 7)) << 3;
      bf16x8 kh0 = *(const bf16x8*)&cK[l32 * 64 + sw];
      bf16x8 kh1 = *(const bf16x8*)&cK[(32 + l32) * 64 + sw];
      acc0 = mfma32(kh0, qh[ks], acc0);
      acc1 = mfma32(kh1, qh[ks], acc1);
    }

    bf16x8 pa0, pa1, pa2, pa3;
    exppack(acc0, ls4, pa0, pa1);
    exppack(acc1, ls4, pa2, pa3);

    // PV: octx[d-block] += P(a) @ V^T(b)
#pragma unroll
    for (int js = 0; js < 4; js++) {
      bf16x8 pj = js == 0 ? pa0 : js == 1 ? pa1 : js == 2 ? pa2 : pa3;
      int vsw = ((js * 2 + g) ^ (l32 & 7)) << 3;
      bf16x8 vh0 = *(const bf16x8*)&cV[l32 * 64 + vsw];
      bf16x8 vh1 = *(const bf16x8*)&cV[(32 + l32) * 64 + vsw];
      octx0 = mfma32(pj, vh0, octx0);
      octx1 = mfma32(pj, vh1, octx1);
    }
    __syncthreads();                     // drains prefetch vmcnt; LDS reuse safe
  }

  // partial lsum per q (combine g halves)
  float lsum = (ls4[0] + ls4[1]) + (ls4[2] + ls4[3]);
  float ls = lsum + __shfl_xor(lsum, 32, 64);
  if (g == 0) Lp[half * 65536 + bh * 2048 + q0 + l32] = ls;

  // partial octx f32
  float* P = Pp + (size_t)half * 4194304u;
#pragma unroll
  for (int r = 0; r < 16; r++) {
    int q = (r & 3) + 8 * (r >> 2) + 4 * g;
    size_t pb = ((size_t)bh * 2048 + q0 + q) * 64;
    P[pb + l32] = octx0[r];
    P[pb + 32 + l32] = octx1[r];
  }
}

// ---------- combine halves, normalize, split ctx to bf16 hi/lo (x4 vec) ----------
__global__ __launch_bounds__(256) void k_reduce(const float* __restrict__ Pp,
                                                const float* __restrict__ Lp,
                                                ushortT* __restrict__ ctxH,
                                                ushortT* __restrict__ ctxL) {
  const unsigned i4 = (blockIdx.x * 256 + threadIdx.x) * 4;
  const int d = i4 & 63;
  const int sq = (i4 >> 6) & 2047;
  const int bh = i4 >> 17;
  float ls = Lp[bh * 2048 + sq] + Lp[65536 + bh * 2048 + sq];
  float inv = 1.0f / ls;
  float4 a = *(const float4*)&Pp[i4];
  float4 b = *(const float4*)&Pp[4194304u + i4];
  float os[4] = {(a.x + b.x) * inv, (a.y + b.y) * inv,
                 (a.z + b.z) * inv, (a.w + b.w) * inv};
  ushort4 h4, l4;
#pragma unroll
  for (int c = 0; c < 4; c++) {
    ushortT hh, ll;
    bsplit(os[c], hh, ll);
    ((ushortT*)&h4)[c] = hh;
    ((ushortT*)&l4)[c] = ll;
  }
  size_t ci = ((size_t)((bh >> 4) * 2048 + sq)) * 1024 + (bh & 15) * 64 + d;
  *(ushort4*)&ctxH[ci] = h4;
  *(ushort4*)&ctxL[ci] = l4;
}

extern "C" void kernel_launch(void* const* d_in, const int* in_sizes, int n_in,
                              void* d_out, int out_size, void* d_ws, size_t ws_size,
                              hipStream_t stream) {
  const float* query = (const float*)d_in[0];
  const float* key   = (const float*)d_in[1];
  const float* value = (const float*)d_in[2];
  const float* Wq = (const float*)d_in[3];
  const float* bq = (const float*)d_in[4];
  const float* Wk = (const float*)d_in[5];
  const float* bk = (const float*)d_in[6];
  const float* Wv = (const float*)d_in[7];
  const float* bv = (const float*)d_in[8];
  const float* Wo = (const float*)d_in[9];
  const float* bo = (const float*)d_in[10];
  const float* lng = (const float*)d_in[11];
  const float* lnb = (const float*)d_in[12];
  float* out = (float*)d_out;

  if (ws_size < (size_t)WS_NEEDED) {
    fprintf(stderr, "kernel_launch: ws too small (%zu < %u)\n", ws_size, WS_NEEDED);
    return;
  }

  ushortT* wsu = (ushortT*)d_ws;
  ushortT* Whi = wsu + U_WHI;
  ushortT* Wlo = wsu + U_WLO;
  ushortT* Xq  = wsu + U_XQ;
  ushortT* Xk  = wsu + U_XK;
  ushortT* Xv  = wsu + U_XV;
  ushortT* Qhp = wsu + U_QH;
  ushortT* Khp = wsu + U_KH;
  ushortT* Vhp = wsu + U_VH;
  ushortT* Chp = wsu + U_XQ;   // ctx hi reuses XQ (free after Q gemm)
  ushortT* Clp = wsu + U_XK;   // ctx lo reuses XK (free after K gemm)

  char* wsb = (char*)d_ws;
  float* Pp = (float*)(wsb + P0_OFF);       // [2][32][2048][64] f32 (attn phase)
  float* Lp = (float*)(wsb + LP_OFF);       // [2][32][2048] f32
  unsigned* histG = (unsigned*)(wsb + P0_OFF);  // radix hists (pre-attn phase)
  unsigned long long* sAbs = (unsigned long long*)(wsb + ABS_OFF);
  unsigned long long* sMsk = (unsigned long long*)(wsb + MSK_OFF);
  unsigned* sCnt = (unsigned*)(wsb + CNT_OFF);

  // zero hist region (in P0 space, free until attention) + stat accumulators
  hipMemsetAsync(histG, 0, HIST_BYTES, stream);
  hipMemsetAsync(wsb + ABS_OFF, 0, 96, stream);

  // fused input prep + |W| stats (independent work, one dispatch)
  k_pre<<<13312, 256, 0, stream>>>(query, key, value, lng, lnb,
                                   Wq, Wk, Wv, Wo, Xq, Xk, Xv, sAbs);

  // weight preprocessing: masked stats + 3-pass radix (12/12/8) + W_eff
  k_masked<<<dim3(512, 4), 256, 0, stream>>>(Wq, Wk, Wv, Wo, sAbs, sMsk, sCnt);
  k_histP<0><<<dim3(512, 4), 256, 0, stream>>>(Wq, Wk, Wv, Wo, sAbs, sMsk, sCnt, histG);
  k_histP<1><<<dim3(512, 4), 256, 0, stream>>>(Wq, Wk, Wv, Wo, sAbs, sMsk, sCnt, histG);
  k_histP<2><<<dim3(512, 4), 256, 0, stream>>>(Wq, Wk, Wv, Wo, sAbs, sMsk, sCnt, histG);
  k_weff<<<dim3(1024, 4), 256, 0, stream>>>(Wq, Wk, Wv, Wo, sAbs, sMsk, sCnt, histG,
                                            Whi, Wlo);

  // fused Q/K projections (BK=64, 2 blk/CU), then V (BK=32+Wlo, 3 blk/CU)
  k_gemmP<0, false, false, 64, 2><<<1024, 256, 0, stream>>>(
      Xq, nullptr, Xk, Whi, nullptr, bq, bk, Qhp, Khp, nullptr);
  k_gemmP<2, false, true, 32, 3><<<512, 256, 0, stream>>>(
      Xv, nullptr, nullptr, Whi + 2 * NW_ELEM, Wlo + 2 * NW_ELEM, bv, nullptr,
      Vhp, nullptr, nullptr);

  // attention (KV-split x2) -> partials, then combine
  k_attn<<<1024, 256, 0, stream>>>(Qhp, Khp, Vhp, Pp, Lp);
  k_reduce<<<4096, 256, 0, stream>>>(Pp, Lp, Chp, Clp);

  // out projection (split-A x split-W, 3 MFMA, BK=32)
  k_gemmP<1, true, true, 32, 2><<<512, 256, 0, stream>>>(
      Chp, Clp, nullptr, Whi + 3 * NW_ELEM, Wlo + 3 * NW_ELEM, bo, nullptr,
      nullptr, nullptr, out);
}

// Round 14
// 240.490 us; speedup vs baseline: 1.0740x; 1.0740x over previous
//
#include <hip/hip_runtime.h>
#include <stdio.h>
#include <stdint.h>

// Problem constants
#define BB 2
#define SS 2048
#define ED 1024
#define HH 16
#define HDD 64
#define MROWS 4096            // BB*SS
#define NW_ELEM 1048576u      // ED*ED

typedef unsigned short ushortT;
typedef __attribute__((ext_vector_type(8))) short bf16x8;
typedef __attribute__((ext_vector_type(4))) float f32x4;
typedef __attribute__((ext_vector_type(16))) float f32x16;

// ws layout (ushort elems from base)
#define U_WHI 0u
#define U_WLO 4194304u
#define U_XQ  8388608u
#define U_XK  12582912u
#define U_XV  16777216u
#define U_QH  20971520u
#define U_KH  25165824u
#define U_VH  29360128u       // ends at 33554432 ushort = 64 MiB
// byte offsets
#define LP_OFF  33554432u     // lsum partials (512 KB) inside freed XV region
#define P0_OFF  67108864u     // partial octx half0, f32, 16 MiB
#define P1_OFF  83886080u     // partial octx half1, f32, 16 MiB (ends 96 MiB)
#define SMALL_OFF  100663296u
#define HIST_OFF   SMALL_OFF                 // 4 passes * 4 w * 256 bins * 4B
#define ABS_OFF    (SMALL_OFF + 16384u)
#define MSK_OFF    (ABS_OFF + 32u)
#define CNT_OFF    (MSK_OFF + 32u)
#define SMALL_BYTES 16464u
#define WS_NEEDED  (SMALL_OFF + SMALL_BYTES)

#define SC44 17592186044416.0f               // 2^44
#define INV44 (1.0 / 17592186044416.0)
#define QSCALE 0.18033688011112042f          // 0.125 * log2(e)

__device__ __forceinline__ const float* wsel(int w, const float* W0, const float* W1,
                                             const float* W2, const float* W3) {
  return w == 0 ? W0 : w == 1 ? W1 : w == 2 ? W2 : W3;
}

// bf16 RTNE helpers
__device__ __forceinline__ ushortT f2bf(float x) {
  unsigned u = __float_as_uint(x);
  unsigned r = (u + 0x7FFFu + ((u >> 16) & 1u)) >> 16;
  return (ushortT)r;
}
__device__ __forceinline__ float bf2f(ushortT b) {
  return __uint_as_float(((unsigned)b) << 16);
}
__device__ __forceinline__ void bsplit(float x, ushortT& h, ushortT& l) {
  ushortT hb = f2bf(x);
  float hf = bf2f(hb);
  h = hb;
  l = f2bf(x - hf);
}
__device__ __forceinline__ unsigned pkbf(float a, float b) {
  unsigned r;
  asm("v_cvt_pk_bf16_f32 %0, %1, %2" : "=v"(r) : "v"(a), "v"(b));
  return r;
}
__device__ __forceinline__ void plswap(unsigned& a, unsigned& b) {
  asm("v_permlane32_swap_b32 %0, %1" : "+v"(a), "+v"(b));
}
// raw 2^x. MUST be compiler-visible (TRANS-use hazard needs wait states) —
// bare inline-asm v_exp_f32 caused sporadic stale reads (R8 failure).
__device__ __forceinline__ float fexp2(float x) {
#if __has_builtin(__builtin_amdgcn_exp2f)
  return __builtin_amdgcn_exp2f(x);
#else
  float r;
  asm("v_exp_f32 %0, %1\n\ts_nop 1" : "=v"(r) : "v"(x));
  return r;
#endif
}

// async global->LDS, 16B/lane
__device__ __forceinline__ void gld_lds16(const ushortT* g, ushortT* s) {
  __builtin_amdgcn_global_load_lds((__attribute__((address_space(1))) void*)g,
                                   (__attribute__((address_space(3))) void*)s, 16, 0, 0);
}

// counted vmem wait (literal immediates only)
template <int N> __device__ __forceinline__ void waitv() {
  if constexpr (N == 0) asm volatile("s_waitcnt vmcnt(0)" ::: "memory");
  else if constexpr (N == 4) asm volatile("s_waitcnt vmcnt(4)" ::: "memory");
  else if constexpr (N == 6) asm volatile("s_waitcnt vmcnt(6)" ::: "memory");
}
__device__ __forceinline__ void pipe_barrier() {
  __builtin_amdgcn_s_barrier();
  __builtin_amdgcn_sched_barrier(0);
}

__device__ __forceinline__ float get_thr(const unsigned long long* sAbs, int w) {
  return 0.7f * (float)((double)sAbs[w] * INV44 / 1048576.0);
}
__device__ __forceinline__ float get_scale(const unsigned long long* sMsk,
                                           const unsigned* cnt, int w) {
  double s = (double)sMsk[w] * INV44;
  return (float)s / fmaxf((float)cnt[w], 1.0f);
}

// parallel radix-select step
__device__ __forceinline__ void scan_sel(const unsigned* hist, unsigned& k, unsigned& prefix,
                                         unsigned* sh, int t) {
  sh[t] = hist[t];
  __syncthreads();
  for (int off = 1; off < 256; off <<= 1) {
    unsigned add = (t + off < 256) ? sh[t + off] : 0u;
    __syncthreads();
    sh[t] += add;
    __syncthreads();
  }
  int sel = __syncthreads_count((int)(sh[t] >= k)) - 1;
  unsigned suf = sh[sel];
  k -= (suf - hist[sel]);
  prefix = (prefix << 8) | (unsigned)sel;
  __syncthreads();
}

// ---------- input prep helpers ----------
__device__ __forceinline__ void ln_unit(const float* __restrict__ query,
                                        const float* __restrict__ g,
                                        const float* __restrict__ b,
                                        ushortT* __restrict__ Xq,
                                        int row, int t, float* red) {
  float4 v = *(const float4*)&query[(size_t)row * ED + t * 4];
  float s = v.x + v.y + v.z + v.w;
#pragma unroll
  for (int m = 32; m; m >>= 1) s += __shfl_xor(s, m, 64);
  if ((t & 63) == 0) red[t >> 6] = s;
  __syncthreads();
  float mu = (red[0] + red[1] + red[2] + red[3]) * (1.0f / 1024.0f);
  float dx = v.x - mu, dy = v.y - mu, dz = v.z - mu, dw = v.w - mu;
  float s2 = dx * dx + dy * dy + dz * dz + dw * dw;
#pragma unroll
  for (int m = 32; m; m >>= 1) s2 += __shfl_xor(s2, m, 64);
  if ((t & 63) == 0) red[4 + (t >> 6)] = s2;
  __syncthreads();
  float var = (red[4] + red[5] + red[6] + red[7]) * (1.0f / 1024.0f);
  float inv = rsqrtf(var + 1e-5f);
  float4 gg = *(const float4*)&g[t * 4];
  float4 bb = *(const float4*)&b[t * 4];
  float ys[4] = {dx * inv * gg.x + bb.x, dy * inv * gg.y + bb.y,
                 dz * inv * gg.z + bb.z, dw * inv * gg.w + bb.w};
  ushort4 h4;
#pragma unroll
  for (int c = 0; c < 4; c++) ((ushortT*)&h4)[c] = f2bf(ys[c]);
  *(ushort4*)&Xq[(size_t)row * ED + t * 4] = h4;
}

__device__ __forceinline__ void cast_unit(const float* __restrict__ src,
                                          ushortT* __restrict__ dst, int idx, int t) {
  const int i = (idx * 256 + t) * 4;
  float4 v = *(const float4*)&src[i];
  ushort4 h4;
  h4.x = f2bf(v.x); h4.y = f2bf(v.y); h4.z = f2bf(v.z); h4.w = f2bf(v.w);
  *(ushort4*)&dst[i] = h4;
}

// ---------- fused: LN(query)/cast(key,value) + |W| stats (independent work) ----------
// grid 13312: [0,4096) LN rows, [4096,8192) key, [8192,12288) value,
// [12288,13312) weight-chunk |W| partial sums (c = bid-12288, w = c>>8).
__global__ __launch_bounds__(256) void k_pre(const float* __restrict__ query,
                                             const float* __restrict__ key,
                                             const float* __restrict__ value,
                                             const float* __restrict__ g,
                                             const float* __restrict__ b,
                                             const float* W0, const float* W1,
                                             const float* W2, const float* W3,
                                             ushortT* __restrict__ Xq,
                                             ushortT* __restrict__ Xk,
                                             ushortT* __restrict__ Xv,
                                             unsigned long long* sAbs) {
  const int t = threadIdx.x, bid = blockIdx.x;
  __shared__ float red[8];
  __shared__ unsigned long long sd[256];
  if (bid < 4096) {
    ln_unit(query, g, b, Xq, bid, t, red);
  } else if (bid < 8192) {
    cast_unit(key, Xk, bid - 4096, t);
  } else if (bid < 12288) {
    cast_unit(value, Xv, bid - 8192, t);
  } else {
    const int c = bid - 12288, w = c >> 8;
    const float* W = wsel(w, W0, W1, W2, W3) + (c & 255) * 4096;
    unsigned long long s = 0;
#pragma unroll
    for (int r = 0; r < 4; r++) {
      float4 v = *(const float4*)(W + (t + 256 * r) * 4);
      s += (unsigned long long)(fabsf(v.x) * SC44);
      s += (unsigned long long)(fabsf(v.y) * SC44);
      s += (unsigned long long)(fabsf(v.z) * SC44);
      s += (unsigned long long)(fabsf(v.w) * SC44);
    }
    sd[t] = s;
    __syncthreads();
    for (int off = 128; off > 0; off >>= 1) {
      if (t < off) sd[t] += sd[t + off];
      __syncthreads();
    }
    if (!t) atomicAdd(&sAbs[w], sd[0]);
  }
}

// ---------- masked sum/count ----------
__global__ __launch_bounds__(256) void k_masked(const float* W0, const float* W1,
                                                const float* W2, const float* W3,
                                                const unsigned long long* sAbs,
                                                unsigned long long* sMsk, unsigned* sCnt) {
  const int w = blockIdx.y, t = threadIdx.x;
  const float thr = get_thr(sAbs, w);
  const float* W = wsel(w, W0, W1, W2, W3) + blockIdx.x * 4096;
  unsigned long long s = 0;
  unsigned c = 0;
#pragma unroll
  for (int r = 0; r < 4; r++) {
    float4 v = *(const float4*)(W + (t + 256 * r) * 4);
    float xs[4] = {v.x, v.y, v.z, v.w};
#pragma unroll
    for (int q = 0; q < 4; q++) {
      float a = fabsf(xs[q]);
      if (a > thr) { s += (unsigned long long)(a * SC44); c++; }
    }
  }
  __shared__ unsigned long long sd[256];
  __shared__ unsigned sc[256];
  sd[t] = s; sc[t] = c;
  __syncthreads();
  for (int off = 128; off > 0; off >>= 1) {
    if (t < off) { sd[t] += sd[t + off]; sc[t] += sc[t + off]; }
    __syncthreads();
  }
  if (!t) { atomicAdd(&sMsk[w], sd[0]); atomicAdd(&sCnt[w], sc[0]); }
}

// ---------- radix histogram pass ----------
__global__ __launch_bounds__(256) void k_hist(const float* W0, const float* W1,
                                              const float* W2, const float* W3,
                                              const unsigned long long* sAbs,
                                              const unsigned long long* sMsk,
                                              const unsigned* sCnt,
                                              unsigned* histG, int pass) {
  const int w = blockIdx.y, t = threadIdx.x;
  __shared__ unsigned sh[256];
  __shared__ unsigned h[256];
  const float thr = get_thr(sAbs, w);
  const float scale = get_scale(sMsk, sCnt, w);
  unsigned k = (w == 3) ? 104857u : 52428u, prefix = 0u;
  for (int pp = 0; pp < pass; pp++)
    scan_sel(histG + (pp * 4 + w) * 256, k, prefix, sh, t);

  h[t] = 0;
  __syncthreads();
  const float* W = wsel(w, W0, W1, W2, W3) + blockIdx.x * 4096;
  const int shift1 = 32 - 8 * pass;
  const int shift2 = 24 - 8 * pass;
#pragma unroll
  for (int r = 0; r < 4; r++) {
    float4 v = *(const float4*)(W + (t + 256 * r) * 4);
    float xs[4] = {v.x, v.y, v.z, v.w};
#pragma unroll
    for (int q = 0; q < 4; q++) {
      float x = xs[q];
      float a = fabsf(x);
      float wq = (a > thr) ? copysignf(scale, x) : 0.0f;
      unsigned bits = __float_as_uint(fabsf(x - wq));
      if (pass == 0) {
        atomicAdd(&h[bits >> 24], 1u);
      } else {
        if ((bits >> shift1) == prefix)
          atomicAdd(&h[(bits >> shift2) & 255u], 1u);
      }
    }
  }
  __syncthreads();
  if (h[t]) atomicAdd(&histG[(pass * 4 + w) * 256 + t], h[t]);
}

// ---------- build W_eff, split to bf16 hi/lo ----------
__global__ __launch_bounds__(256) void k_weff(const float* W0, const float* W1,
                                              const float* W2, const float* W3,
                                              const unsigned long long* sAbs,
                                              const unsigned long long* sMsk,
                                              const unsigned* sCnt,
                                              const unsigned* histG,
                                              ushortT* Whi, ushortT* Wlo) {
  const int w = blockIdx.y, t = threadIdx.x;
  __shared__ unsigned sh[256];
  const float thr = get_thr(sAbs, w);
  const float scale = get_scale(sMsk, sCnt, w);
  unsigned k = (w == 3) ? 104857u : 52428u, kth = 0u;
  for (int pp = 0; pp < 4; pp++)
    scan_sel(histG + (pp * 4 + w) * 256, k, kth, sh, t);

  const unsigned idx = (blockIdx.x * 256 + t) * 4;
  const float* W = wsel(w, W0, W1, W2, W3);
  float4 v = *(const float4*)(W + idx);
  float xs[4] = {v.x, v.y, v.z, v.w};
  ushort4 h4, l4;
#pragma unroll
  for (int c = 0; c < 4; c++) {
    float x = xs[c];
    float a = fabsf(x);
    float wq = (a > thr) ? copysignf(scale, x) : 0.0f;
    float res = x - wq;
    unsigned bits = __float_as_uint(fabsf(res));
    float we = wq + ((bits >= kth) ? res : 0.0f);
    ushortT hh, ll;
    bsplit(we, hh, ll);
    ((ushortT*)&h4)[c] = hh;
    ((ushortT*)&l4)[c] = ll;
  }
  *(ushort4*)&Whi[(size_t)w * NW_ELEM + idx] = h4;
  *(ushort4*)&Wlo[(size_t)w * NW_ELEM + idx] = l4;
}

// ---------- pipelined MFMA GEMM (3-buffer, counted vmcnt) ----------
__device__ __forceinline__ f32x4 mfma16(bf16x8 a, bf16x8 b, f32x4 c) {
  return __builtin_amdgcn_mfma_f32_16x16x32_bf16(a, b, c, 0, 0, 0);
}

template <int MODE, bool ALO, bool WLO, int BK, int MINW>
__global__ __launch_bounds__(256, MINW) void k_gemmP(
    const ushortT* __restrict__ A0, const ushortT* __restrict__ A0l,
    const ushortT* __restrict__ A1,
    const ushortT* __restrict__ Wh, const ushortT* __restrict__ Wl,
    const float* __restrict__ bias0, const float* __restrict__ bias1,
    ushortT* __restrict__ Cb0, ushortT* __restrict__ Cb1,
    float* __restrict__ Cf) {
  constexpr int ABUF = (BK == 64) ? 8192 : 4096;
  constexpr int BBUF = (BK == 64) ? 4096 : 2048;
  constexpr int L = ((BK == 64) ? 4 : 2) * (1 + (ALO ? 1 : 0)) +
                    ((BK == 64) ? 2 : 1) * (1 + (WLO ? 1 : 0));
  constexpr int NT = 1024 / BK;
  __shared__ __align__(16) ushortT sAh[3 * ABUF];
  __shared__ __align__(16) ushortT sAl[ALO ? 3 * ABUF : 8];
  __shared__ __align__(16) ushortT sBh[3 * BBUF];
  __shared__ __align__(16) ushortT sBl[WLO ? 3 * BBUF : 8];

  const int t = threadIdx.x;
  const int w = t >> 6, l = t & 63;
  const int wr = w >> 1, wc = w & 1;

  const int which = (MODE == 0) ? (blockIdx.x >> 9) : 0;
  const int wid = blockIdx.x & 511;
  int id2 = (wid & 7) * 64 + (wid >> 3);   // XCD-chunked, bijective
  const int m0 = (id2 >> 4) * 128, n0 = (id2 & 15) * 64;

  const ushortT* A = (MODE == 0 && which) ? A1 : A0;
  const ushortT* Wha = Wh + (MODE == 0 ? (unsigned)which * NW_ELEM : 0u);
  const float* bias = (MODE == 0 && which) ? bias1 : bias0;

  // staging swizzles
  const int sr = l >> 3, swz = (l & 7) ^ sr;              // BK=64
  const int srow = l >> 2, sgr = (l & 3) ^ ((l >> 3) & 3); // BK=32

  auto stage = [&](int kt, int buf) {
    if constexpr (BK == 64) {
#pragma unroll
      for (int s2 = 0; s2 < 4; s2++) {
        int seg = w * 4 + s2;
        size_t ga = (size_t)(m0 + seg * 8 + sr) * ED + kt * 64 + swz * 8;
        gld_lds16(A + ga, sAh + buf * ABUF + seg * 512);
        if constexpr (ALO) gld_lds16(A0l + ga, sAl + buf * ABUF + seg * 512);
      }
#pragma unroll
      for (int s2 = 0; s2 < 2; s2++) {
        int seg = w * 2 + s2;
        size_t gb = (size_t)(n0 + seg * 8 + sr) * ED + kt * 64 + swz * 8;
        gld_lds16(Wha + gb, sBh + buf * BBUF + seg * 512);
        if constexpr (WLO) gld_lds16(Wl + gb, sBl + buf * BBUF + seg * 512);
      }
    } else {
#pragma unroll
      for (int s2 = 0; s2 < 2; s2++) {
        int seg = w * 2 + s2;
        size_t ga = (size_t)(m0 + seg * 16 + srow) * ED + kt * 32 + sgr * 8;
        gld_lds16(A + ga, sAh + buf * ABUF + seg * 512);
        if constexpr (ALO) gld_lds16(A0l + ga, sAl + buf * ABUF + seg * 512);
      }
      {
        size_t gb = (size_t)(n0 + w * 16 + srow) * ED + kt * 32 + sgr * 8;
        gld_lds16(Wha + gb, sBh + buf * BBUF + w * 512);
        if constexpr (WLO) gld_lds16(Wl + gb, sBl + buf * BBUF + w * 512);
      }
    }
  };

  f32x4 acc[4][2];
#pragma unroll
  for (int i = 0; i < 4; i++)
#pragma unroll
    for (int j = 0; j < 2; j++) acc[i][j] = (f32x4){0.0f, 0.0f, 0.0f, 0.0f};

  auto compute = [&](int buf) {
    if constexpr (BK == 64) {
#pragma unroll
      for (int ks = 0; ks < 2; ks++) {
        bf16x8 ah[4], al[4], bh2[2], bl2[2];
        const int G = ks * 4 + (l >> 4);
#pragma unroll
        for (int i = 0; i < 4; i++) {
          int r = wr * 64 + i * 16 + (l & 15);
          int off = buf * ABUF + r * 64 + ((G ^ (l & 7)) << 3);
          ah[i] = *(const bf16x8*)&sAh[off];
          if constexpr (ALO) al[i] = *(const bf16x8*)&sAl[off];
        }
#pragma unroll
        for (int j = 0; j < 2; j++) {
          int r = wc * 32 + j * 16 + (l & 15);
          int off = buf * BBUF + r * 64 + ((G ^ (l & 7)) << 3);
          bh2[j] = *(const bf16x8*)&sBh[off];
          if constexpr (WLO) bl2[j] = *(const bf16x8*)&sBl[off];
        }
#pragma unroll
        for (int i = 0; i < 4; i++)
#pragma unroll
          for (int j = 0; j < 2; j++) {
            acc[i][j] = mfma16(ah[i], bh2[j], acc[i][j]);
            if constexpr (WLO) acc[i][j] = mfma16(ah[i], bl2[j], acc[i][j]);
            if constexpr (ALO) acc[i][j] = mfma16(al[i], bh2[j], acc[i][j]);
          }
      }
    } else {
      bf16x8 ah[4], al[4], bh2[2], bl2[2];
      const int G = l >> 4;
#pragma unroll
      for (int i = 0; i < 4; i++) {
        int r = wr * 64 + i * 16 + (l & 15);
        int off = buf * ABUF + r * 32 + ((G ^ ((r >> 1) & 3)) << 3);
        ah[i] = *(const bf16x8*)&sAh[off];
        if constexpr (ALO) al[i] = *(const bf16x8*)&sAl[off];
      }
#pragma unroll
      for (int j = 0; j < 2; j++) {
        int r = wc * 32 + j * 16 + (l & 15);
        int off = buf * BBUF + r * 32 + ((G ^ ((r >> 1) & 3)) << 3);
        bh2[j] = *(const bf16x8*)&sBh[off];
        if constexpr (WLO) bl2[j] = *(const bf16x8*)&sBl[off];
      }
#pragma unroll
      for (int i = 0; i < 4; i++)
#pragma unroll
        for (int j = 0; j < 2; j++) {
          acc[i][j] = mfma16(ah[i], bh2[j], acc[i][j]);
          if constexpr (WLO) acc[i][j] = mfma16(ah[i], bl2[j], acc[i][j]);
          if constexpr (ALO) acc[i][j] = mfma16(al[i], bh2[j], acc[i][j]);
        }
    }
  };

  // 3-buffer pipeline, counted vmcnt, raw barriers
  stage(0, 0);
  stage(1, 1);
  for (int kt = 0; kt < NT; ++kt) {
    if (kt < NT - 1) waitv<L>(); else waitv<0>();
    pipe_barrier();
    if (kt + 2 < NT) stage(kt + 2, (kt + 2) % 3);
    __builtin_amdgcn_s_setprio(1);
    compute(kt % 3);
    __builtin_amdgcn_s_setprio(0);
  }

  // epilogue
  const int coln = l & 15, row4 = (l >> 4) * 4;
  float bn[2];
#pragma unroll
  for (int j = 0; j < 2; j++) bn[j] = bias[n0 + wc * 32 + j * 16 + coln];
  const int b_ = m0 >> 11, h_ = n0 >> 6;

  if constexpr (MODE == 1) {
#pragma unroll
    for (int i = 0; i < 4; i++)
#pragma unroll
      for (int j = 0; j < 2; j++) {
        int n = n0 + wc * 32 + j * 16 + coln;
#pragma unroll
        for (int r = 0; r < 4; r++) {
          int m = m0 + wr * 64 + i * 16 + row4 + r;
          Cf[(size_t)m * ED + n] = acc[i][j][r] + bn[j];
        }
      }
  } else if constexpr (MODE == 0) {
    const float osc = (which == 0) ? QSCALE : 1.0f;
    ushortT* C = which ? Cb1 : Cb0;
#pragma unroll
    for (int i = 0; i < 4; i++)
#pragma unroll
      for (int j = 0; j < 2; j++) {
        int hd = wc * 32 + j * 16 + coln;
#pragma unroll
        for (int r = 0; r < 4; r++) {
          int m = m0 + wr * 64 + i * 16 + row4 + r;
          int s_ = m & 2047;
          float y = acc[i][j][r] + bn[j];
          y = (fabsf(y) >= 0.05f) ? y : 0.0f;
          y *= osc;
          C[((size_t)(b_ * HH + h_) * SS + s_) * HDD + hd] = f2bf(y);
        }
      }
  } else {  // MODE 2: V transposed [B,H,HD,S]
#pragma unroll
    for (int i = 0; i < 4; i++)
#pragma unroll
      for (int j = 0; j < 2; j++) {
        int hd = wc * 32 + j * 16 + coln;
        int s0_ = (m0 + wr * 64 + i * 16 + row4) & 2047;
        ushort4 h4;
#pragma unroll
        for (int r = 0; r < 4; r++) {
          float y = acc[i][j][r] + bn[j];
          y = (fabsf(y) >= 0.05f) ? y : 0.0f;
          ((ushortT*)&h4)[r] = f2bf(y);
        }
        *(ushort4*)&Cb0[((size_t)(b_ * HH + h_) * HDD + hd) * SS + s0_] = h4;
      }
  }
}

// ---------- MFMA flash attention: KV-split x2, 2-buffer, builtin exp2 ----------
__device__ __forceinline__ f32x16 mfma32(bf16x8 a, bf16x8 b, f32x16 c) {
  return __builtin_amdgcn_mfma_f32_32x32x16_bf16(a, b, c, 0, 0, 0);
}

// exp (Q pre-scaled by SCALE*log2e) + pack acc into two PV a-frags
__device__ __forceinline__ void exppack(const f32x16& A, float* ls4,
                                        bf16x8& paA, bf16x8& paB) {
  float p[16];
#pragma unroll
  for (int r = 0; r < 16; r++) {
    p[r] = fexp2(A[r]);
    ls4[r & 3] += p[r];
  }
  unsigned c0 = pkbf(p[0], p[1]), c1 = pkbf(p[2], p[3]);
  unsigned c2 = pkbf(p[4], p[5]), c3 = pkbf(p[6], p[7]);
  unsigned c4 = pkbf(p[8], p[9]), c5 = pkbf(p[10], p[11]);
  unsigned c6 = pkbf(p[12], p[13]), c7 = pkbf(p[14], p[15]);
  plswap(c0, c2); plswap(c1, c3); plswap(c4, c6); plswap(c5, c7);
  uint4 ta = make_uint4(c0, c1, c2, c3);
  uint4 tb = make_uint4(c4, c5, c6, c7);
  paA = __builtin_bit_cast(bf16x8, ta);
  paB = __builtin_bit_cast(bf16x8, tb);
}

__global__ __launch_bounds__(256, 4) void k_attn(
    const ushortT* __restrict__ Qh, const ushortT* __restrict__ Kh,
    const ushortT* __restrict__ Vh,
    float* __restrict__ Pp, float* __restrict__ Lp) {
  __shared__ __align__(16) ushortT sK[2 * 4096];
  __shared__ __align__(16) ushortT sV[2 * 4096];

  const int t = threadIdx.x;
  const int w = t >> 6, l = t & 63;
  const int l32 = l & 31, g = l >> 5;

  int id = blockIdx.x;
  int id2 = (id & 7) * 128 + (id >> 3);   // 1024 = 8*128, bijective
  const int bh = id2 >> 5;
  const int qt = (id2 >> 1) & 15;
  const int half = id2 & 1;

  const size_t kqbase = (size_t)bh * (SS * HDD);   // Q,K: [bh][s][64]
  const size_t vbase = (size_t)bh * (HDD * SS);    // V^T: [bh][64][s]
  const int q0 = qt * 128 + w * 32;
  const int sbase = half * 1024;

  bf16x8 qh[4];
  const size_t qrow = kqbase + (size_t)(q0 + l32) * HDD;
#pragma unroll
  for (int ks = 0; ks < 4; ks++) qh[ks] = *(const bf16x8*)&Qh[qrow + ks * 16 + g * 8];

  f32x16 octx0, octx1;
#pragma unroll
  for (int i = 0; i < 16; i++) { octx0[i] = 0.0f; octx1[i] = 0.0f; }
  float ls4[4] = {0.0f, 0.0f, 0.0f, 0.0f};

  const int srow = l >> 3;
  const int sgr = (l & 7) ^ srow;

  auto stageA = [&](int kt, int buf) {
    const int s0 = sbase + kt * 64;
#pragma unroll
    for (int s2 = 0; s2 < 2; s2++) {
      int seg = w * 2 + s2;
      int row = seg * 8 + srow;
      gld_lds16(Kh + kqbase + (size_t)(s0 + row) * HDD + sgr * 8, sK + buf * 4096 + seg * 512);
      gld_lds16(Vh + vbase + (size_t)row * SS + s0 + sgr * 8, sV + buf * 4096 + seg * 512);
    }
  };

  stageA(0, 0);
  __syncthreads();                       // implicit vmcnt(0) drain

  for (int kt = 0; kt < 16; ++kt) {
    if (kt < 15) stageA(kt + 1, (kt + 1) & 1);
    const ushortT* cK = sK + (kt & 1) * 4096;
    const ushortT* cV = sV + (kt & 1) * 4096;

    // QK^T swapped: acc = mfma(A=K, B=Q) -> lane = q-col, rows = j
    f32x16 acc0, acc1;
#pragma unroll
    for (int i = 0; i < 16; i++) { acc0[i] = 0.0f; acc1[i] = 0.0f; }
#pragma unroll
    for (int ks = 0; ks < 4; ks++) {
      int sw = ((ks * 2 + g) ^ (l32 & 7)) << 3;
      bf16x8 kh0 = *(const bf16x8*)&cK[l32 * 64 + sw];
      bf16x8 kh1 = *(const bf16x8*)&cK[(32 + l32) * 64 + sw];
      acc0 = mfma32(kh0, qh[ks], acc0);
      acc1 = mfma32(kh1, qh[ks], acc1);
    }

    bf16x8 pa0, pa1, pa2, pa3;
    exppack(acc0, ls4, pa0, pa1);
    exppack(acc1, ls4, pa2, pa3);

    // PV: octx[d-block] += P(a) @ V^T(b)
#pragma unroll
    for (int js = 0; js < 4; js++) {
      bf16x8 pj = js == 0 ? pa0 : js == 1 ? pa1 : js == 2 ? pa2 : pa3;
      int vsw = ((js * 2 + g) ^ (l32 & 7)) << 3;
      bf16x8 vh0 = *(const bf16x8*)&cV[l32 * 64 + vsw];
      bf16x8 vh1 = *(const bf16x8*)&cV[(32 + l32) * 64 + vsw];
      octx0 = mfma32(pj, vh0, octx0);
      octx1 = mfma32(pj, vh1, octx1);
    }
    __syncthreads();                     // drains prefetch vmcnt; LDS reuse safe
  }

  // partial lsum per q (combine g halves)
  float lsum = (ls4[0] + ls4[1]) + (ls4[2] + ls4[3]);
  float ls = lsum + __shfl_xor(lsum, 32, 64);
  if (g == 0) Lp[half * 65536 + bh * 2048 + q0 + l32] = ls;

  // partial octx f32
  float* P = Pp + (size_t)half * 4194304u;
#pragma unroll
  for (int r = 0; r < 16; r++) {
    int q = (r & 3) + 8 * (r >> 2) + 4 * g;
    size_t pb = ((size_t)bh * 2048 + q0 + q) * 64;
    P[pb + l32] = octx0[r];
    P[pb + 32 + l32] = octx1[r];
  }
}

// ---------- combine halves, normalize, split ctx to bf16 hi/lo (x4 vec) ----------
__global__ __launch_bounds__(256) void k_reduce(const float* __restrict__ Pp,
                                                const float* __restrict__ Lp,
                                                ushortT* __restrict__ ctxH,
                                                ushortT* __restrict__ ctxL) {
  const unsigned i4 = (blockIdx.x * 256 + threadIdx.x) * 4;
  const int d = i4 & 63;
  const int sq = (i4 >> 6) & 2047;
  const int bh = i4 >> 17;
  float ls = Lp[bh * 2048 + sq] + Lp[65536 + bh * 2048 + sq];
  float inv = 1.0f / ls;
  float4 a = *(const float4*)&Pp[i4];
  float4 b = *(const float4*)&Pp[4194304u + i4];
  float os[4] = {(a.x + b.x) * inv, (a.y + b.y) * inv,
                 (a.z + b.z) * inv, (a.w + b.w) * inv};
  ushort4 h4, l4;
#pragma unroll
  for (int c = 0; c < 4; c++) {
    ushortT hh, ll;
    bsplit(os[c], hh, ll);
    ((ushortT*)&h4)[c] = hh;
    ((ushortT*)&l4)[c] = ll;
  }
  size_t ci = ((size_t)((bh >> 4) * 2048 + sq)) * 1024 + (bh & 15) * 64 + d;
  *(ushort4*)&ctxH[ci] = h4;
  *(ushort4*)&ctxL[ci] = l4;
}

extern "C" void kernel_launch(void* const* d_in, const int* in_sizes, int n_in,
                              void* d_out, int out_size, void* d_ws, size_t ws_size,
                              hipStream_t stream) {
  const float* query = (const float*)d_in[0];
  const float* key   = (const float*)d_in[1];
  const float* value = (const float*)d_in[2];
  const float* Wq = (const float*)d_in[3];
  const float* bq = (const float*)d_in[4];
  const float* Wk = (const float*)d_in[5];
  const float* bk = (const float*)d_in[6];
  const float* Wv = (const float*)d_in[7];
  const float* bv = (const float*)d_in[8];
  const float* Wo = (const float*)d_in[9];
  const float* bo = (const float*)d_in[10];
  const float* lng = (const float*)d_in[11];
  const float* lnb = (const float*)d_in[12];
  float* out = (float*)d_out;

  if (ws_size < (size_t)WS_NEEDED) {
    fprintf(stderr, "kernel_launch: ws too small (%zu < %u)\n", ws_size, WS_NEEDED);
    return;
  }

  ushortT* wsu = (ushortT*)d_ws;
  ushortT* Whi = wsu + U_WHI;
  ushortT* Wlo = wsu + U_WLO;
  ushortT* Xq  = wsu + U_XQ;
  ushortT* Xk  = wsu + U_XK;
  ushortT* Xv  = wsu + U_XV;
  ushortT* Qhp = wsu + U_QH;
  ushortT* Khp = wsu + U_KH;
  ushortT* Vhp = wsu + U_VH;
  ushortT* Chp = wsu + U_XQ;   // ctx hi reuses XQ (free after Q gemm)
  ushortT* Clp = wsu + U_XK;   // ctx lo reuses XK (free after K gemm)

  char* wsb = (char*)d_ws;
  float* Pp = (float*)(wsb + P0_OFF);       // [2][32][2048][64] f32
  float* Lp = (float*)(wsb + LP_OFF);       // [2][32][2048] f32
  unsigned* histG = (unsigned*)(wsb + HIST_OFF);
  unsigned long long* sAbs = (unsigned long long*)(wsb + ABS_OFF);
  unsigned long long* sMsk = (unsigned long long*)(wsb + MSK_OFF);
  unsigned* sCnt = (unsigned*)(wsb + CNT_OFF);

  // zero hist/stat accumulators (replay-safe)
  hipMemsetAsync(histG, 0, SMALL_BYTES, stream);

  // fused input prep + |W| stats (independent work, one dispatch)
  k_pre<<<13312, 256, 0, stream>>>(query, key, value, lng, lnb,
                                   Wq, Wk, Wv, Wo, Xq, Xk, Xv, sAbs);

  // weight preprocessing chain
  dim3 gW(256, 4);
  k_masked<<<gW, 256, 0, stream>>>(Wq, Wk, Wv, Wo, sAbs, sMsk, sCnt);
  for (int pass = 0; pass < 4; ++pass)
    k_hist<<<gW, 256, 0, stream>>>(Wq, Wk, Wv, Wo, sAbs, sMsk, sCnt, histG, pass);
  k_weff<<<dim3(1024, 4), 256, 0, stream>>>(Wq, Wk, Wv, Wo, sAbs, sMsk, sCnt, histG,
                                            Whi, Wlo);

  // fused Q/K projections (BK=64, 2 blk/CU), then V (BK=32+Wlo, 3 blk/CU)
  k_gemmP<0, false, false, 64, 2><<<1024, 256, 0, stream>>>(
      Xq, nullptr, Xk, Whi, nullptr, bq, bk, Qhp, Khp, nullptr);
  k_gemmP<2, false, true, 32, 3><<<512, 256, 0, stream>>>(
      Xv, nullptr, nullptr, Whi + 2 * NW_ELEM, Wlo + 2 * NW_ELEM, bv, nullptr,
      Vhp, nullptr, nullptr);

  // attention (KV-split x2) -> partials, then combine
  k_attn<<<1024, 256, 0, stream>>>(Qhp, Khp, Vhp, Pp, Lp);
  k_reduce<<<4096, 256, 0, stream>>>(Pp, Lp, Chp, Clp);

  // out projection (split-A x split-W, 3 MFMA, BK=32)
  k_gemmP<1, true, true, 32, 2><<<512, 256, 0, stream>>>(
      Chp, Clp, nullptr, Whi + 3 * NW_ELEM, Wlo + 3 * NW_ELEM, bo, nullptr,
      nullptr, nullptr, out);
}